// Round 1
// baseline (568.040 us; speedup 1.0000x reference)
//
#include <hip/hip_runtime.h>
#include <hip/hip_fp16.h>
#include <stdint.h>

#define GENES 5000
#define NH1   4000
#define NH2   2000
#define NH3   1000
#define NPATH 200
#define NLAB  50
#define NROWS 8192
#define KP    100   // genes per pathway

typedef _Float16 f16x2 __attribute__((ext_vector_type(2)));
union H2U { unsigned int u; f16x2 v; __half2 h; };

__device__ __forceinline__ float dot2acc(unsigned int a, unsigned int b, float c){
#if __has_builtin(__builtin_amdgcn_fdot2)
    H2U ua; ua.u = a; H2U ub; ub.u = b;
    return __builtin_amdgcn_fdot2(ua.v, ub.v, c, false);
#else
    H2U ua; ua.u = a; H2U ub; ub.u = b;
    float2 fa = __half22float2(ua.h), fb = __half22float2(ub.h);
    return fmaf(fa.x, fb.x, fmaf(fa.y, fb.y, c));
#endif
}

// ---------------- prep: extract pathway gene indices from m1 ----------------
__global__ void k_idx(const float* __restrict__ m1, int* __restrict__ idx1){
    __shared__ int cnt;
    if (threadIdx.x == 0) cnt = 0;
    __syncthreads();
    const float* row = m1 + (size_t)blockIdx.x * 20 * GENES;   // first row of this pathway's 20
    for (int g = threadIdx.x; g < GENES; g += blockDim.x){
        if (row[g] != 0.0f){
            int pos = atomicAdd(&cnt, 1);
            if (pos < KP) idx1[blockIdx.x * KP + pos] = g;
        }
    }
}

// ------------- prep: gather w1 -> packed f16 [kk][c][u*2+kpar], BN-scaled ----
__global__ void k_wg1(const float* __restrict__ w1, const float* __restrict__ gamma1,
                      const float* __restrict__ rv1, const int* __restrict__ idx1,
                      __half* __restrict__ wg1p){
    int tid = blockIdx.x * 256 + threadIdx.x;
    if (tid >= 400000) return;
    int kk  = tid / 8000;
    int rem = tid % 8000;
    int c = rem >> 3;          // 0..999  (c = p*5+g)
    int e = rem & 7;           // u*2 + kpar
    int p = c / 5, g = c % 5;
    int u = e >> 1, kpar = e & 1;
    int k = kk * 2 + kpar;
    int j = p * 20 + g * 4 + u;
    int col = idx1[p * KP + k];
    float a = gamma1[j] * rsqrtf(rv1[j] + 1e-5f);
    wg1p[tid] = (__half)(w1[(size_t)j * GENES + col] * a);
}

// ------------- prep: small gathers + BN folds + wc transpose ----------------
__global__ void k_prep(const float* __restrict__ w2, const float* __restrict__ b2,
                       const float* __restrict__ w3, const float* __restrict__ b3,
                       const float* __restrict__ w4, const float* __restrict__ wc,
                       const float* __restrict__ gamma1, const float* __restrict__ beta1,
                       const float* __restrict__ rm1, const float* __restrict__ rv1,
                       const float* __restrict__ gamma2, const float* __restrict__ beta2,
                       const float* __restrict__ rm2, const float* __restrict__ rv2,
                       const float* __restrict__ gamma3, const float* __restrict__ beta3,
                       const float* __restrict__ rm3, const float* __restrict__ rv3,
                       const float* __restrict__ b1,
                       float* __restrict__ bf1, float* __restrict__ wg2, float* __restrict__ bf2,
                       float* __restrict__ wg3, float* __restrict__ bf3,
                       float* __restrict__ wg4, float* __restrict__ wcT){
    int t = blockIdx.x * 256 + threadIdx.x;
    if (t < 40000){                                     // wg2[k][j], k<20, j<2000
        int k = t / NH2, j = t % NH2, p = j / 10;
        float a = gamma2[j] * rsqrtf(rv2[j] + 1e-5f);
        wg2[t] = w2[(size_t)j * NH1 + 20 * p + k] * a;
    } else if (t < 50000){                              // wg3[k][j], k<10, j<1000
        int i = t - 40000;
        int k = i / NH3, j = i % NH3, p = j / 5;
        float a = gamma3[j] * rsqrtf(rv3[j] + 1e-5f);
        wg3[i] = w3[(size_t)j * NH2 + 10 * p + k] * a;
    } else if (t < 51000){                              // wg4[k][q], k<5, q<200 (no BN)
        int i = t - 50000;
        int k = i / NPATH, q = i % NPATH;
        wg4[i] = w4[(size_t)q * NH3 + 5 * q + k];
    } else if (t < 61000){                              // wcT[q][n]
        int i = t - 51000;
        int q = i / NLAB, n = i % NLAB;
        wcT[i] = wc[(size_t)n * NPATH + q];
    } else if (t < 65000){                              // bf1[j] (layout == [c][u])
        int j = t - 61000;
        float a = gamma1[j] * rsqrtf(rv1[j] + 1e-5f);
        bf1[j] = a * b1[j] + beta1[j] - rm1[j] * a;
    } else if (t < 67000){
        int j = t - 65000;
        float a = gamma2[j] * rsqrtf(rv2[j] + 1e-5f);
        bf2[j] = a * b2[j] + beta2[j] - rm2[j] * a;
    } else if (t < 68000){
        int j = t - 67000;
        float a = gamma3[j] * rsqrtf(rv3[j] + 1e-5f);
        bf3[j] = a * b3[j] + beta3[j] - rm3[j] * a;
    }
}

// ---------------- layer 1: sparse gather GEMM, 4 rows/block -----------------
__global__ __launch_bounds__(256) void k_layer1(const float* __restrict__ x,
        const int* __restrict__ idx1, const __half* __restrict__ wg1p,
        const float* __restrict__ bf1, __half* __restrict__ h1buf){
    __shared__ __align__(16) __half xs[GENES * 4];      // [col][4 rows] f16, 40 KB
    const int r0 = blockIdx.x * 4;
    for (int c = threadIdx.x; c < GENES; c += 256){
        float v0 = x[(size_t)(r0 + 0) * GENES + c];
        float v1 = x[(size_t)(r0 + 1) * GENES + c];
        float v2 = x[(size_t)(r0 + 2) * GENES + c];
        float v3 = x[(size_t)(r0 + 3) * GENES + c];
        __half2* d = (__half2*)(xs + c * 4);
        d[0] = __floats2half2_rn(v0, v1);
        d[1] = __floats2half2_rn(v2, v3);
    }
    __syncthreads();
    const int t = threadIdx.x;
    if (t >= 250) return;
    const int pl = t / 5, g = t % 5;
    for (int pass = 0; pass < 4; ++pass){
        const int p = pass * 50 + pl;
        float acc[4][4];
        #pragma unroll
        for (int u = 0; u < 4; ++u)
            #pragma unroll
            for (int r = 0; r < 4; ++r) acc[u][r] = 0.0f;
        const int2* ip = (const int2*)(idx1 + p * KP);
        const uint4* wp = ((const uint4*)wg1p) + (p * 5 + g);
        for (int kk = 0; kk < 50; ++kk){
            int2 iv = ip[kk];
            uint2 xa = *(const uint2*)(xs + iv.x * 4);  // 4 rows @ k0
            uint2 xb = *(const uint2*)(xs + iv.y * 4);  // 4 rows @ k1
            uint4 wv = wp[(size_t)kk * 1000];           // 4 units x (k0,k1) f16
            unsigned pr[4];
            pr[0] = (xa.x & 0xffffu) | (xb.x << 16);
            pr[1] = (xa.x >> 16)     | (xb.x & 0xffff0000u);
            pr[2] = (xa.y & 0xffffu) | (xb.y << 16);
            pr[3] = (xa.y >> 16)     | (xb.y & 0xffff0000u);
            const unsigned wu[4] = {wv.x, wv.y, wv.z, wv.w};
            #pragma unroll
            for (int u = 0; u < 4; ++u)
                #pragma unroll
                for (int r = 0; r < 4; ++r)
                    acc[u][r] = dot2acc(pr[r], wu[u], acc[u][r]);
        }
        const float4 bf = ((const float4*)bf1)[p * 5 + g];
        const float bfa[4] = {bf.x, bf.y, bf.z, bf.w};
        const int jb = p * 20 + g * 4;
        #pragma unroll
        for (int r = 0; r < 4; ++r){
            __half2 o01 = __floats2half2_rn(fmaxf(acc[0][r] + bfa[0], 0.0f),
                                            fmaxf(acc[1][r] + bfa[1], 0.0f));
            __half2 o23 = __floats2half2_rn(fmaxf(acc[2][r] + bfa[2], 0.0f),
                                            fmaxf(acc[3][r] + bfa[3], 0.0f));
            uint2 st; st.x = *(unsigned*)&o01; st.y = *(unsigned*)&o23;
            *(uint2*)(h1buf + (size_t)(r0 + r) * NH1 + jb) = st;
        }
    }
}

// ---------------- layers 2..5 fused, 4 rows/block ---------------------------
__global__ __launch_bounds__(256) void k_tail(const __half* __restrict__ h1buf,
        const float* __restrict__ wg2, const float* __restrict__ bf2,
        const float* __restrict__ wg3, const float* __restrict__ bf3,
        const float* __restrict__ wg4, const float* __restrict__ b4,
        const float* __restrict__ wcT, const float* __restrict__ bc,
        float* __restrict__ out){
    __shared__ __align__(16) __half h1s[4 * NH1];   // 32 KB
    __shared__ __half h2s[4 * NH2];                 // 16 KB
    __shared__ __half h3s[4 * NH3];                 //  8 KB
    __shared__ float  scs[4 * NPATH];               // 3.2 KB
    const int r0 = blockIdx.x * 4;
    {
        const uint4* src = (const uint4*)(h1buf + (size_t)r0 * NH1);
        uint4* dst = (uint4*)h1s;
        for (int i = threadIdx.x; i < 2000; i += 256) dst[i] = src[i];
    }
    __syncthreads();
    for (int j = threadIdx.x; j < NH2; j += 256){
        const int base = (j / 10) * 20;
        float a0 = 0, a1 = 0, a2 = 0, a3 = 0;
        for (int k = 0; k < 20; ++k){
            float w = wg2[k * NH2 + j];
            a0 = fmaf(w, (float)h1s[0 * NH1 + base + k], a0);
            a1 = fmaf(w, (float)h1s[1 * NH1 + base + k], a1);
            a2 = fmaf(w, (float)h1s[2 * NH1 + base + k], a2);
            a3 = fmaf(w, (float)h1s[3 * NH1 + base + k], a3);
        }
        float b = bf2[j];
        h2s[0 * NH2 + j] = (__half)fmaxf(a0 + b, 0.0f);
        h2s[1 * NH2 + j] = (__half)fmaxf(a1 + b, 0.0f);
        h2s[2 * NH2 + j] = (__half)fmaxf(a2 + b, 0.0f);
        h2s[3 * NH2 + j] = (__half)fmaxf(a3 + b, 0.0f);
    }
    __syncthreads();
    for (int j = threadIdx.x; j < NH3; j += 256){
        const int base = (j / 5) * 10;
        float a0 = 0, a1 = 0, a2 = 0, a3 = 0;
        for (int k = 0; k < 10; ++k){
            float w = wg3[k * NH3 + j];
            a0 = fmaf(w, (float)h2s[0 * NH2 + base + k], a0);
            a1 = fmaf(w, (float)h2s[1 * NH2 + base + k], a1);
            a2 = fmaf(w, (float)h2s[2 * NH2 + base + k], a2);
            a3 = fmaf(w, (float)h2s[3 * NH2 + base + k], a3);
        }
        float b = bf3[j];
        h3s[0 * NH3 + j] = (__half)fmaxf(a0 + b, 0.0f);
        h3s[1 * NH3 + j] = (__half)fmaxf(a1 + b, 0.0f);
        h3s[2 * NH3 + j] = (__half)fmaxf(a2 + b, 0.0f);
        h3s[3 * NH3 + j] = (__half)fmaxf(a3 + b, 0.0f);
    }
    __syncthreads();
    if (threadIdx.x < NPATH){
        const int j = threadIdx.x;
        const int base = 5 * j;
        float a0 = 0, a1 = 0, a2 = 0, a3 = 0;
        for (int k = 0; k < 5; ++k){
            float w = wg4[k * NPATH + j];
            a0 = fmaf(w, (float)h3s[0 * NH3 + base + k], a0);
            a1 = fmaf(w, (float)h3s[1 * NH3 + base + k], a1);
            a2 = fmaf(w, (float)h3s[2 * NH3 + base + k], a2);
            a3 = fmaf(w, (float)h3s[3 * NH3 + base + k], a3);
        }
        float b = b4[j];
        scs[0 * NPATH + j] = fmaxf(a0 + b, 0.0f);
        scs[1 * NPATH + j] = fmaxf(a1 + b, 0.0f);
        scs[2 * NPATH + j] = fmaxf(a2 + b, 0.0f);
        scs[3 * NPATH + j] = fmaxf(a3 + b, 0.0f);
    }
    __syncthreads();
    if (threadIdx.x < 200){
        const int r = threadIdx.x / NLAB, n = threadIdx.x % NLAB;
        float acc = bc[n];
        const float* sp = scs + r * NPATH;
        for (int q = 0; q < NPATH; ++q)
            acc = fmaf(sp[q], wcT[q * NLAB + n], acc);
        out[(size_t)(r0 + r) * NLAB + n] = acc;
    }
}

extern "C" void kernel_launch(void* const* d_in, const int* in_sizes, int n_in,
                              void* d_out, int out_size, void* d_ws, size_t ws_size,
                              hipStream_t stream){
    (void)in_sizes; (void)n_in; (void)out_size; (void)ws_size;
    const float* x      = (const float*)d_in[0];
    const float* w1     = (const float*)d_in[1];
    const float* b1     = (const float*)d_in[2];
    const float* m1     = (const float*)d_in[3];
    const float* w2     = (const float*)d_in[4];
    const float* b2     = (const float*)d_in[5];
    const float* w3     = (const float*)d_in[7];
    const float* b3     = (const float*)d_in[8];
    const float* w4     = (const float*)d_in[10];
    const float* b4     = (const float*)d_in[11];
    const float* gamma1 = (const float*)d_in[13];
    const float* beta1  = (const float*)d_in[14];
    const float* rm1    = (const float*)d_in[15];
    const float* rv1    = (const float*)d_in[16];
    const float* gamma2 = (const float*)d_in[17];
    const float* beta2  = (const float*)d_in[18];
    const float* rm2    = (const float*)d_in[19];
    const float* rv2    = (const float*)d_in[20];
    const float* gamma3 = (const float*)d_in[21];
    const float* beta3  = (const float*)d_in[22];
    const float* rm3    = (const float*)d_in[23];
    const float* rv3    = (const float*)d_in[24];
    const float* wc     = (const float*)d_in[25];
    const float* bc     = (const float*)d_in[26];

    char* ws = (char*)d_ws;
    size_t off = 0;
    __half* h1buf = (__half*)(ws + off); off += (size_t)NROWS * NH1 * 2;  // 65.536 MB
    int*    idx1  = (int*)  (ws + off);  off += (size_t)NPATH * KP * 4;   // 80 KB
    __half* wg1p  = (__half*)(ws + off); off += (size_t)400000 * 2;       // 800 KB
    float*  bf1   = (float*)(ws + off);  off += (size_t)NH1 * 4;
    float*  wg2   = (float*)(ws + off);  off += (size_t)40000 * 4;
    float*  bf2   = (float*)(ws + off);  off += (size_t)NH2 * 4;
    float*  wg3   = (float*)(ws + off);  off += (size_t)10000 * 4;
    float*  bf3   = (float*)(ws + off);  off += (size_t)NH3 * 4;
    float*  wg4   = (float*)(ws + off);  off += (size_t)1000 * 4;
    float*  wcT   = (float*)(ws + off);  off += (size_t)10000 * 4;

    hipLaunchKernelGGL(k_idx,    dim3(NPATH),    dim3(256), 0, stream, m1, idx1);
    hipLaunchKernelGGL(k_wg1,    dim3(1563),     dim3(256), 0, stream, w1, gamma1, rv1, idx1, wg1p);
    hipLaunchKernelGGL(k_prep,   dim3(266),      dim3(256), 0, stream,
                       w2, b2, w3, b3, w4, wc,
                       gamma1, beta1, rm1, rv1, gamma2, beta2, rm2, rv2,
                       gamma3, beta3, rm3, rv3, b1,
                       bf1, wg2, bf2, wg3, bf3, wg4, wcT);
    hipLaunchKernelGGL(k_layer1, dim3(NROWS/4),  dim3(256), 0, stream, x, idx1, wg1p, bf1, h1buf);
    hipLaunchKernelGGL(k_tail,   dim3(NROWS/4),  dim3(256), 0, stream,
                       h1buf, wg2, bf2, wg3, bf3, wg4, b4, wcT, bc, (float*)d_out);
}

// Round 2
// 538.637 us; speedup vs baseline: 1.0546x; 1.0546x over previous
//
#include <hip/hip_runtime.h>
#include <hip/hip_fp16.h>
#include <stdint.h>

#define GENES 5000
#define NH1   4000
#define NH2   2000
#define NH3   1000
#define NPATH 200
#define NLAB  50
#define NROWS 8192
#define KP    100   // genes per pathway

typedef _Float16 f16x2 __attribute__((ext_vector_type(2)));
union H2U { unsigned int u; f16x2 v; __half2 h; };

__device__ __forceinline__ float dot2acc(unsigned int a, unsigned int b, float c){
#if __has_builtin(__builtin_amdgcn_fdot2)
    H2U ua; ua.u = a; H2U ub; ub.u = b;
    return __builtin_amdgcn_fdot2(ua.v, ub.v, c, false);
#else
    H2U ua; ua.u = a; H2U ub; ub.u = b;
    float2 fa = __half22float2(ua.h), fb = __half22float2(ub.h);
    return fmaf(fa.x, fb.x, fmaf(fa.y, fb.y, c));
#endif
}

// pack (lo16 of xa, lo16 of xb) -> one dword; and (hi16, hi16)
__device__ __forceinline__ unsigned pklo(unsigned xa, unsigned xb){
#if __has_builtin(__builtin_amdgcn_perm)
    return __builtin_amdgcn_perm(xb, xa, 0x05040100u);
#else
    return (xa & 0xffffu) | (xb << 16);
#endif
}
__device__ __forceinline__ unsigned pkhi(unsigned xa, unsigned xb){
#if __has_builtin(__builtin_amdgcn_perm)
    return __builtin_amdgcn_perm(xb, xa, 0x07060302u);
#else
    return (xa >> 16) | (xb & 0xffff0000u);
#endif
}

// ---------------- prep: extract pathway gene indices from m1 ----------------
__global__ void k_idx(const float* __restrict__ m1, int* __restrict__ idx1){
    __shared__ int cnt;
    if (threadIdx.x == 0) cnt = 0;
    __syncthreads();
    const float* row = m1 + (size_t)blockIdx.x * 20 * GENES;
    for (int g = threadIdx.x; g < GENES; g += blockDim.x){
        if (row[g] != 0.0f){
            int pos = atomicAdd(&cnt, 1);
            if (pos < KP) idx1[blockIdx.x * KP + pos] = g;
        }
    }
}

// ------------- prep: gather w1 -> packed f16 [kk][c][u*2+kpar], BN-scaled ----
__global__ void k_wg1(const float* __restrict__ w1, const float* __restrict__ gamma1,
                      const float* __restrict__ rv1, const int* __restrict__ idx1,
                      __half* __restrict__ wg1p){
    int tid = blockIdx.x * 256 + threadIdx.x;
    if (tid >= 400000) return;
    int kk  = tid / 8000;
    int rem = tid % 8000;
    int c = rem >> 3;          // 0..999  (c = p*5+g)
    int e = rem & 7;           // u*2 + kpar
    int p = c / 5, g = c % 5;
    int u = e >> 1, kpar = e & 1;
    int k = kk * 2 + kpar;
    int j = p * 20 + g * 4 + u;
    int col = idx1[p * KP + k];
    float a = gamma1[j] * rsqrtf(rv1[j] + 1e-5f);
    wg1p[tid] = (__half)(w1[(size_t)j * GENES + col] * a);
}

// ------------- prep: BN folds + packed pathway weight cones + wc transpose --
__global__ void k_prep(const float* __restrict__ w2, const float* __restrict__ b2,
                       const float* __restrict__ w3, const float* __restrict__ b3,
                       const float* __restrict__ w4, const float* __restrict__ wc,
                       const float* __restrict__ gamma1, const float* __restrict__ beta1,
                       const float* __restrict__ rm1, const float* __restrict__ rv1,
                       const float* __restrict__ gamma2, const float* __restrict__ beta2,
                       const float* __restrict__ rm2, const float* __restrict__ rv2,
                       const float* __restrict__ gamma3, const float* __restrict__ beta3,
                       const float* __restrict__ rm3, const float* __restrict__ rv3,
                       const float* __restrict__ b1,
                       float* __restrict__ bf1, float* __restrict__ bf2,
                       float* __restrict__ bf3,
                       __half* __restrict__ wpk, float* __restrict__ wcT){
    int t = blockIdx.x * 256 + threadIdx.x;
    if (t < 40000){                      // cone: w2 part, f16 idx i = u2*20+k
        int p = t / 200, i = t % 200;
        int u2 = i / 20, k = i % 20;
        int j = 10 * p + u2;
        float a = gamma2[j] * rsqrtf(rv2[j] + 1e-5f);
        wpk[p * 256 + i] = (__half)(w2[(size_t)j * NH1 + 20 * p + k] * a);
    } else if (t < 50000){               // cone: w3 part at 200 + u3*10 + k
        int i2 = t - 40000;
        int p = i2 / 50, i = i2 % 50;
        int u3 = i / 10, k = i % 10;
        int j = 5 * p + u3;
        float a = gamma3[j] * rsqrtf(rv3[j] + 1e-5f);
        wpk[p * 256 + 200 + i] = (__half)(w3[(size_t)j * NH2 + 10 * p + k] * a);
    } else if (t < 51000){               // cone: w4 part at 250 + k
        int i2 = t - 50000;
        int p = i2 / 5, k = i2 % 5;
        wpk[p * 256 + 250 + k] = (__half)(w4[(size_t)p * NH3 + 5 * p + k]);
    } else if (t < 51200){               // pad slot 255
        int p = t - 51000;
        wpk[p * 256 + 255] = (__half)0.0f;
    } else if (t < 61200){               // wcT[q][n]
        int i = t - 51200;
        int q = i / NLAB, n = i % NLAB;
        wcT[i] = wc[(size_t)n * NPATH + q];
    } else if (t < 65200){               // bf1
        int j = t - 61200;
        float a = gamma1[j] * rsqrtf(rv1[j] + 1e-5f);
        bf1[j] = a * b1[j] + beta1[j] - rm1[j] * a;
    } else if (t < 67200){               // bf2
        int j = t - 65200;
        float a = gamma2[j] * rsqrtf(rv2[j] + 1e-5f);
        bf2[j] = a * b2[j] + beta2[j] - rm2[j] * a;
    } else if (t < 68200){               // bf3
        int j = t - 67200;
        float a = gamma3[j] * rsqrtf(rv3[j] + 1e-5f);
        bf3[j] = a * b3[j] + beta3[j] - rm3[j] * a;
    }
}

// ---------------- layer 1: sparse gather GEMM, 4 rows/block, pipelined ------
__global__ __launch_bounds__(256) void k_layer1(const float* __restrict__ x,
        const int* __restrict__ idx1, const __half* __restrict__ wg1p,
        const float* __restrict__ bf1, __half* __restrict__ h1buf){
    __shared__ __align__(16) __half xs[GENES * 4];      // [col][4 rows] f16, 40 KB
    const int r0 = blockIdx.x * 4;
    for (int c = threadIdx.x; c < GENES; c += 256){
        float v0 = x[(size_t)(r0 + 0) * GENES + c];
        float v1 = x[(size_t)(r0 + 1) * GENES + c];
        float v2 = x[(size_t)(r0 + 2) * GENES + c];
        float v3 = x[(size_t)(r0 + 3) * GENES + c];
        __half2* d = (__half2*)(xs + c * 4);
        d[0] = __floats2half2_rn(v0, v1);
        d[1] = __floats2half2_rn(v2, v3);
    }
    __syncthreads();
    const int t = threadIdx.x;
    if (t >= 250) return;
    const int pl = t / 5, g = t % 5;
    for (int pass = 0; pass < 4; ++pass){
        const int p = pass * 50 + pl;
        float acc[4][4];
        #pragma unroll
        for (int u = 0; u < 4; ++u)
            #pragma unroll
            for (int r = 0; r < 4; ++r) acc[u][r] = 0.0f;
        const int2* ip = (const int2*)(idx1 + p * KP);
        const char* wb = (const char*)(((const uint4*)wg1p) + (p * 5 + g));
        int2 ivA = ip[0], ivB = ip[1];
        uint4 wvA = *(const uint4*)wb;
        uint4 wvB = *(const uint4*)(wb + 16000);
        for (int kk = 0; kk < 50; kk += 2){
            // branchless prefetch of next pair (clamped to 0 on last iter)
            const int nk = (kk + 2 < 50) ? kk + 2 : 0;
            int2 ivA2 = ip[nk], ivB2 = ip[nk + 1];
            uint4 wvA2 = *(const uint4*)(wb + (size_t)nk * 16000);
            uint4 wvB2 = *(const uint4*)(wb + (size_t)(nk + 1) * 16000);
            {
                uint2 xa = *(const uint2*)(xs + ivA.x * 4);
                uint2 xb = *(const uint2*)(xs + ivA.y * 4);
                unsigned pr[4] = { pklo(xa.x, xb.x), pkhi(xa.x, xb.x),
                                   pklo(xa.y, xb.y), pkhi(xa.y, xb.y) };
                const unsigned wu[4] = {wvA.x, wvA.y, wvA.z, wvA.w};
                #pragma unroll
                for (int u = 0; u < 4; ++u)
                    #pragma unroll
                    for (int r = 0; r < 4; ++r)
                        acc[u][r] = dot2acc(pr[r], wu[u], acc[u][r]);
            }
            {
                uint2 xa = *(const uint2*)(xs + ivB.x * 4);
                uint2 xb = *(const uint2*)(xs + ivB.y * 4);
                unsigned pr[4] = { pklo(xa.x, xb.x), pkhi(xa.x, xb.x),
                                   pklo(xa.y, xb.y), pkhi(xa.y, xb.y) };
                const unsigned wu[4] = {wvB.x, wvB.y, wvB.z, wvB.w};
                #pragma unroll
                for (int u = 0; u < 4; ++u)
                    #pragma unroll
                    for (int r = 0; r < 4; ++r)
                        acc[u][r] = dot2acc(pr[r], wu[u], acc[u][r]);
            }
            ivA = ivA2; ivB = ivB2; wvA = wvA2; wvB = wvB2;
        }
        const float4 bf = ((const float4*)bf1)[p * 5 + g];
        const float bfa[4] = {bf.x, bf.y, bf.z, bf.w};
        const int jb = p * 20 + g * 4;
        #pragma unroll
        for (int r = 0; r < 4; ++r){
            __half2 o01 = __floats2half2_rn(fmaxf(acc[0][r] + bfa[0], 0.0f),
                                            fmaxf(acc[1][r] + bfa[1], 0.0f));
            __half2 o23 = __floats2half2_rn(fmaxf(acc[2][r] + bfa[2], 0.0f),
                                            fmaxf(acc[3][r] + bfa[3], 0.0f));
            uint2 st; st.x = *(unsigned*)&o01; st.y = *(unsigned*)&o23;
            *(uint2*)(h1buf + (size_t)(r0 + r) * NH1 + jb) = st;
        }
    }
}

// -------- layers 2..5: register cone, thread = pathway, 8 rows/block --------
__global__ __launch_bounds__(256) void k_tail(const __half* __restrict__ h1buf,
        const __half* __restrict__ wpk, const float* __restrict__ bf2,
        const float* __restrict__ bf3, const float* __restrict__ b4,
        const float* __restrict__ wcT, const float* __restrict__ bc,
        float* __restrict__ out){
    __shared__ float scs[8 * NPATH];                    // 6.4 KB
    __shared__ __align__(16) float wcs[NPATH * NLAB];   // 40 KB
    const int t = threadIdx.x;
    const int r0 = blockIdx.x * 8;
    for (int i = t; i < (NPATH * NLAB) / 4; i += 256)
        ((float4*)wcs)[i] = ((const float4*)wcT)[i];
    if (t < NPATH){
        const int p = t;
        unsigned cw[128];                               // 256 f16 cone weights
        const uint4* wp4 = (const uint4*)(wpk + p * 256);
        #pragma unroll
        for (int i = 0; i < 32; ++i){
            uint4 v = wp4[i];
            cw[4*i] = v.x; cw[4*i+1] = v.y; cw[4*i+2] = v.z; cw[4*i+3] = v.w;
        }
        float c2[10], c3[5];
        #pragma unroll
        for (int i = 0; i < 10; ++i) c2[i] = bf2[10 * p + i];
        #pragma unroll
        for (int i = 0; i < 5; ++i)  c3[i] = bf3[5 * p + i];
        const float b4p = b4[p];
        for (int r = 0; r < 8; ++r){
            const uint2* hp = (const uint2*)(h1buf + (size_t)(r0 + r) * NH1 + 20 * p);
            unsigned h1u[10];
            #pragma unroll
            for (int i = 0; i < 5; ++i){ uint2 v = hp[i]; h1u[2*i] = v.x; h1u[2*i+1] = v.y; }
            unsigned h2u[5];
            #pragma unroll
            for (int i = 0; i < 5; ++i){
                float a0 = c2[2*i], a1 = c2[2*i+1];
                #pragma unroll
                for (int kk = 0; kk < 10; ++kk){
                    a0 = dot2acc(h1u[kk], cw[(2*i) * 10 + kk], a0);
                    a1 = dot2acc(h1u[kk], cw[(2*i+1) * 10 + kk], a1);
                }
                __half2 hh = __floats2half2_rn(fmaxf(a0, 0.f), fmaxf(a1, 0.f));
                h2u[i] = *(unsigned*)&hh;
            }
            float h3f[5];
            #pragma unroll
            for (int u = 0; u < 5; ++u){
                float a = c3[u];
                #pragma unroll
                for (int kk = 0; kk < 5; ++kk)
                    a = dot2acc(h2u[kk], cw[100 + u * 5 + kk], a);
                h3f[u] = fmaxf(a, 0.f);
            }
            unsigned h3u[3];
            __half2 t01 = __floats2half2_rn(h3f[0], h3f[1]); h3u[0] = *(unsigned*)&t01;
            __half2 t23 = __floats2half2_rn(h3f[2], h3f[3]); h3u[1] = *(unsigned*)&t23;
            __half2 t4  = __floats2half2_rn(h3f[4], 0.f);    h3u[2] = *(unsigned*)&t4;
            float a = b4p;
            #pragma unroll
            for (int kk = 0; kk < 3; ++kk)
                a = dot2acc(h3u[kk], cw[125 + kk], a);
            scs[r * NPATH + p] = fmaxf(a, 0.f);
        }
    }
    __syncthreads();
    for (int o = t; o < 8 * NLAB; o += 256){
        int r = o / NLAB, n = o % NLAB;
        float acc = bc[n];
        const float* sp = scs + r * NPATH;
        #pragma unroll 8
        for (int q = 0; q < NPATH; ++q)
            acc = fmaf(sp[q], wcs[q * NLAB + n], acc);
        out[(size_t)(r0 + r) * NLAB + n] = acc;
    }
}

extern "C" void kernel_launch(void* const* d_in, const int* in_sizes, int n_in,
                              void* d_out, int out_size, void* d_ws, size_t ws_size,
                              hipStream_t stream){
    (void)in_sizes; (void)n_in; (void)out_size; (void)ws_size;
    const float* x      = (const float*)d_in[0];
    const float* w1     = (const float*)d_in[1];
    const float* b1     = (const float*)d_in[2];
    const float* m1     = (const float*)d_in[3];
    const float* w2     = (const float*)d_in[4];
    const float* b2     = (const float*)d_in[5];
    const float* w3     = (const float*)d_in[7];
    const float* b3     = (const float*)d_in[8];
    const float* w4     = (const float*)d_in[10];
    const float* b4     = (const float*)d_in[11];
    const float* gamma1 = (const float*)d_in[13];
    const float* beta1  = (const float*)d_in[14];
    const float* rm1    = (const float*)d_in[15];
    const float* rv1    = (const float*)d_in[16];
    const float* gamma2 = (const float*)d_in[17];
    const float* beta2  = (const float*)d_in[18];
    const float* rm2    = (const float*)d_in[19];
    const float* rv2    = (const float*)d_in[20];
    const float* gamma3 = (const float*)d_in[21];
    const float* beta3  = (const float*)d_in[22];
    const float* rm3    = (const float*)d_in[23];
    const float* rv3    = (const float*)d_in[24];
    const float* wc     = (const float*)d_in[25];
    const float* bc     = (const float*)d_in[26];

    char* ws = (char*)d_ws;
    size_t off = 0;
    __half* h1buf = (__half*)(ws + off); off += (size_t)NROWS * NH1 * 2;  // 65.536 MB
    int*    idx1  = (int*)  (ws + off);  off += (size_t)NPATH * KP * 4;   // 80 KB
    __half* wg1p  = (__half*)(ws + off); off += (size_t)400000 * 2;       // 800 KB
    float*  bf1   = (float*)(ws + off);  off += (size_t)NH1 * 4;
    float*  bf2   = (float*)(ws + off);  off += (size_t)NH2 * 4;
    float*  bf3   = (float*)(ws + off);  off += (size_t)NH3 * 4;
    __half* wpk   = (__half*)(ws + off); off += (size_t)NPATH * 256 * 2;  // 102.4 KB
    float*  wcT   = (float*)(ws + off);  off += (size_t)NPATH * NLAB * 4; // 40 KB

    hipLaunchKernelGGL(k_idx,    dim3(NPATH),   dim3(256), 0, stream, m1, idx1);
    hipLaunchKernelGGL(k_wg1,    dim3(1563),    dim3(256), 0, stream, w1, gamma1, rv1, idx1, wg1p);
    hipLaunchKernelGGL(k_prep,   dim3(267),     dim3(256), 0, stream,
                       w2, b2, w3, b3, w4, wc,
                       gamma1, beta1, rm1, rv1, gamma2, beta2, rm2, rv2,
                       gamma3, beta3, rm3, rv3, b1,
                       bf1, bf2, bf3, wpk, wcT);
    hipLaunchKernelGGL(k_layer1, dim3(NROWS/4), dim3(256), 0, stream, x, idx1, wg1p, bf1, h1buf);
    hipLaunchKernelGGL(k_tail,   dim3(NROWS/8), dim3(256), 0, stream,
                       h1buf, wpk, bf2, bf3, b4, wcT, bc, (float*)d_out);
}